// Round 9
// baseline (141.676 us; speedup 1.0000x reference)
//
#include <hip/hip_runtime.h>
#include <hip/hip_bf16.h>
#include <math.h>

#define LN_EPS 1e-5f

typedef unsigned short ushortT;
typedef short bf16x8 __attribute__((ext_vector_type(8)));
typedef float f32x4 __attribute__((ext_vector_type(4)));

// ws layout (float offsets)
#define WS_QP   0            // q_p * scale (128)
#define WS_V0   128          // v0 (128)
#define WS_S0   256          // s0 scalar
#define WS_H1P  512          // 16*256 h1 partials
#define WS_PART 4608         // per-block partials: [y 256][m][l][pad] stride 260
#define PART_STRIDE 260
#define PART_M 256
#define PART_L 257
#define WS_Z    107000       // z = Wk @ q_p (256)
#define WS_GP   109000       // 32 x 260 chunk combine
#define GP_STRIDE 260
#define NCOMB   32
#define WS_WPT  131072       // ushort region: wpt panels [32][256m][32k] bf16 (512KB)

__device__ __forceinline__ float elu1(float x){ return x > 0.f ? x : expm1f(x); }
__device__ __forceinline__ unsigned pk2(float lo, float hi){
  union { __hip_bfloat162 h; unsigned u; } cv;
  cv.h = __float22bfloat162_rn(make_float2(lo, hi));
  return cv.u;
}
// async global->LDS DMA, 16B/lane, linear dest (wave-uniform base + lane*16)
__device__ __forceinline__ void dma16(const void* g, void* l) {
  __builtin_amdgcn_global_load_lds(
      (const __attribute__((address_space(1))) unsigned int*)g,
      (__attribute__((address_space(3))) unsigned int*)l, 16, 0, 0);
}
template<int N> __device__ __forceinline__ void vwait() {
  asm volatile("s_waitcnt vmcnt(%0)" :: "i"(N) : "memory");
}
__device__ __forceinline__ void lwait0() {
  asm volatile("s_waitcnt lgkmcnt(0)" ::: "memory");
}
__device__ __forceinline__ void sbar()   { __builtin_amdgcn_s_barrier(); }
__device__ __forceinline__ void schedb() { __builtin_amdgcn_sched_barrier(0); }

// ---------------- K_setup: wpt panels (pre-swizzled) + h1 partial dots ----------------
// wpt panel kc (0..31): ushort idx = kc*8192 + m*32 + ((c ^ ((m>>1)&3))*8 + e)
//   holding Wp[kc*32 + c*8 + e][m] as bf16.  Swizzle baked in -> k_main DMAs verbatim.
__global__ __launch_bounds__(256) void k_setup(
    const float* __restrict__ Wp,
    const float* __restrict__ x, const float* __restrict__ W1, int d_omic,
    ushortT* __restrict__ wpt, float* __restrict__ ws)
{
  int bb = blockIdx.x, t = threadIdx.x;
  if (bb < 32) {
    int kc = bb, m = t, sw = (m >> 1) & 3;
    #pragma unroll
    for (int c = 0; c < 4; ++c) {
      float v[8];
      #pragma unroll
      for (int e = 0; e < 8; ++e) v[e] = Wp[(size_t)(kc * 32 + c * 8 + e) * 256 + m];
      uint4 w = make_uint4(pk2(v[0], v[1]), pk2(v[2], v[3]), pk2(v[4], v[5]), pk2(v[6], v[7]));
      *(uint4*)&wpt[kc * 8192 + m * 32 + ((c ^ sw) * 8)] = w;
    }
  } else {
    int g = bb - 32;
    int i0 = g * 99, i1 = min(i0 + 99, d_omic);
    __shared__ float xs[112];
    for (int i = i0 + t; i < i1; i += 256) xs[i - i0] = x[i];
    __syncthreads();
    float s = 0.f;
    for (int i = i0; i < i1; i++) s = fmaf(xs[i - i0], W1[(size_t)i * 256 + t], s);
    ws[WS_H1P + g * 256 + t] = s;
  }
}

// ---------------- K1: omic MLP + token0 LN1 + q_p/v0/s0 + z = Wk@q_p (fp32) ----------------
__global__ __launch_bounds__(256) void k_omic(
    const float* __restrict__ b1,
    const float* __restrict__ W2, const float* __restrict__ b2,
    const float* __restrict__ Wqkv,
    const float* __restrict__ ln1_g, const float* __restrict__ ln1_b,
    float* __restrict__ ws)
{
  __shared__ float h1[256];
  __shared__ float xn0[256];
  __shared__ float qs[128], ks[128];
  __shared__ float red[8];
  int tid = threadIdx.x, lane = tid & 63, wave = tid >> 6;

  float s = b1[tid];
  for (int g = 0; g < 16; g++) s += ws[WS_H1P + g * 256 + tid];
  h1[tid] = elu1(s);
  __syncthreads();

  s = b2[tid];
  for (int i = 0; i < 256; i++) s = fmaf(h1[i], W2[i * 256 + tid], s);
  float t0 = elu1(s);

  float ps = t0, pq = t0 * t0;
  for (int m = 1; m < 64; m <<= 1) { ps += __shfl_xor(ps, m); pq += __shfl_xor(pq, m); }
  if (lane == 0) { red[wave] = ps; red[4 + wave] = pq; }
  __syncthreads();
  float mu = (red[0] + red[1] + red[2] + red[3]) * (1.f / 256.f);
  float var = (red[4] + red[5] + red[6] + red[7]) * (1.f / 256.f) - mu * mu;
  float xn = (t0 - mu) * rsqrtf(var + LN_EPS) * ln1_g[tid] + ln1_b[tid];
  xn0[tid] = xn;
  __syncthreads();

  float a = 0.f;
  for (int j = 0; j < 256; j++) a = fmaf(xn0[j], Wqkv[j * 384 + tid], a);
  if (tid < 128) { float q = a * 0.088388347648318447f; qs[tid] = q; ws[WS_QP + tid] = q; }
  else           { ks[tid - 128] = a; }
  if (tid < 128) {
    float av = 0.f;
    for (int j = 0; j < 256; j++) av = fmaf(xn0[j], Wqkv[j * 384 + 256 + tid], av);
    ws[WS_V0 + tid] = av;
  }
  __syncthreads();
  float p = (tid < 128) ? qs[tid] * ks[tid] : 0.f;
  for (int m = 1; m < 64; m <<= 1) p += __shfl_xor(p, m);
  if (lane == 0) red[wave] = p;
  __syncthreads();
  if (tid == 0) ws[WS_S0] = red[0] + red[1] + red[2] + red[3];

  // z[c] = sum_d Wk[c][d] * q_scaled[d]  (Wk = Wqkv[:,128:256])
  float zv = 0.f;
  #pragma unroll 4
  for (int d = 0; d < 128; d += 4) {
    float4 q4 = *(const float4*)&qs[d];
    const float* wr_ = &Wqkv[tid * 384 + 128 + d];
    zv = fmaf(q4.x, wr_[0], zv);
    zv = fmaf(q4.y, wr_[1], zv);
    zv = fmaf(q4.z, wr_[2], zv);
    zv = fmaf(q4.w, wr_[3], zv);
  }
  ws[WS_Z + tid] = zv;
}

// ---------------- K2: BM=128, 8-wave: GEMM + LN + dot(z) + softmax + y-reduce ----------------
// Phase 1: T = wsi[128r] @ Wp (K=1024, 32 K32-slices, wsi 3 slots / wpt 2, vwait<6>).
// Tail (registers): xn = LN(T);  s_i = xn_i . z;  softmax;  y = sum_i w_i xn_i.
// LDS U (80KB): wsi slots [0,48K), wpt slots [48K,80K); red at [64K,68K) post-loop;
// tail bufs at U[0,6K).
__global__ __launch_bounds__(512, 4) void k_main(
    const float* __restrict__ wsi, int N,
    const ushortT* __restrict__ wpt,
    const float* __restrict__ bp,
    const float* __restrict__ ln1_g, const float* __restrict__ ln1_b,
    float* __restrict__ ws)
{
  __shared__ __align__(16) char U[81920];

  const int tid = threadIdx.x;
  const int lane = tid & 63, wv = tid >> 6;
  const int l15 = lane & 15, lh = lane >> 4;
  const int cg = wv & 3, rg = wv >> 2;
  const int b = blockIdx.x, r0 = b * 128;

  // ---- DMA source indices ----
  int wsiSrc[2];
  #pragma unroll
  for (int i = 0; i < 2; ++i) {
    int rowL = 16 * wv + 8 * i + (lane >> 3);
    int gr = r0 + rowL; gr = (gr < N) ? gr : (N - 1);
    wsiSrc[i] = gr * 1024 + (((lane & 7) ^ (lane >> 3)) << 2);
  }
  int wptSrc[2];
  #pragma unroll
  for (int j = 0; j < 2; ++j) wptSrc[j] = (32 * wv + 16 * j) * 32 + lane * 8;

  const unsigned afslot = (unsigned)((lh ^ ((l15 >> 1) & 3)) << 4);
  const unsigned bs0 = (unsigned)(((2 * lh)     ^ (l15 & 7)) << 4);
  const unsigned bs1 = (unsigned)(((2 * lh + 1) ^ (l15 & 7)) << 4);

  const f32x4 z4i = {0.f, 0.f, 0.f, 0.f};
  f32x4 acc[4][4];
  #pragma unroll
  for (int mt = 0; mt < 4; ++mt)
    #pragma unroll
    for (int nt = 0; nt < 4; ++nt) acc[mt][nt] = z4i;

  auto stageWsi = [&](int kc, int slot) {
    char* ds = U + slot * 16384 + wv * 2048;
    #pragma unroll
    for (int i = 0; i < 2; ++i) dma16(wsi + wsiSrc[i] + kc * 32, ds + i * 1024);
  };
  auto stageWpt = [&](int kc, int slot) {
    char* dw = U + 49152 + slot * 16384 + wv * 2048;
    #pragma unroll
    for (int j = 0; j < 2; ++j) dma16(wpt + wptSrc[j] + kc * 8192, dw + j * 1024);
  };

  // ---- phase 1: 32 K32-slices ----
  stageWsi(0, 0); stageWpt(0, 0);
  stageWsi(1, 1); stageWpt(1, 1);
  stageWsi(2, 2);
  for (int s = 0; s < 32; ++s) {
    if (s < 30) vwait<6>(); else if (s == 30) vwait<4>(); else vwait<0>();
    sbar(); schedb();
    {
      const char* Ws = U + (s % 3) * 16384;
      const char* Wf = U + 49152 + (s & 1) * 16384;
      bf16x8 af[4], bfr[4];
      #pragma unroll
      for (int mt = 0; mt < 4; ++mt)
        af[mt] = *(const bf16x8*)(Wf + (64 * cg + 16 * mt + l15) * 64 + afslot);
      #pragma unroll
      for (int nt = 0; nt < 4; ++nt) {
        const char* p = Ws + (64 * rg + 16 * nt + l15) * 128;
        uint4 ua = *(const uint4*)(p + bs0);
        uint4 ub = *(const uint4*)(p + bs1);
        union { unsigned u[4]; bf16x8 v; } cv;
        cv.u[0] = pk2(__uint_as_float(ua.x), __uint_as_float(ua.y));
        cv.u[1] = pk2(__uint_as_float(ua.z), __uint_as_float(ua.w));
        cv.u[2] = pk2(__uint_as_float(ub.x), __uint_as_float(ub.y));
        cv.u[3] = pk2(__uint_as_float(ub.z), __uint_as_float(ub.w));
        bfr[nt] = cv.v;
      }
      #pragma unroll
      for (int mt = 0; mt < 4; ++mt)
        #pragma unroll
        for (int nt = 0; nt < 4; ++nt)
          acc[mt][nt] = __builtin_amdgcn_mfma_f32_16x16x32_bf16(af[mt], bfr[nt], acc[mt][nt], 0, 0, 0);
    }
    sbar(); schedb();
    if (s < 30) stageWpt(s + 2, s & 1);
    if (s < 29) stageWsi(s + 3, s % 3);
  }

  // ---- bias + LN1 stats (cross-cg reduction; red at U+64K, free after loop) ----
  float* red = (float*)(U + 65536);
  float4 bp4[4], g4[4], b4[4];
  #pragma unroll
  for (int mt = 0; mt < 4; ++mt) {
    int m0 = 64 * cg + 16 * mt + 4 * lh;
    bp4[mt] = *(const float4*)&bp[m0];
    g4[mt]  = *(const float4*)&ln1_g[m0];
    b4[mt]  = *(const float4*)&ln1_b[m0];
  }
  float ps[4], pq[4];
  #pragma unroll
  for (int nt = 0; nt < 4; ++nt) { ps[nt] = 0.f; pq[nt] = 0.f; }
  #pragma unroll
  for (int mt = 0; mt < 4; ++mt) {
    const float bb4[4] = {bp4[mt].x, bp4[mt].y, bp4[mt].z, bp4[mt].w};
    #pragma unroll
    for (int nt = 0; nt < 4; ++nt)
      #pragma unroll
      for (int r = 0; r < 4; ++r) {
        float v = acc[mt][nt][r] + bb4[r];
        acc[mt][nt][r] = v;
        ps[nt] += v; pq[nt] += v * v;
      }
  }
  #pragma unroll
  for (int nt = 0; nt < 4; ++nt) {
    ps[nt] += __shfl_xor(ps[nt], 16); pq[nt] += __shfl_xor(pq[nt], 16);
    ps[nt] += __shfl_xor(ps[nt], 32); pq[nt] += __shfl_xor(pq[nt], 32);
  }
  if (lh == 0) {
    #pragma unroll
    for (int nt = 0; nt < 4; ++nt) {
      int row = 64 * rg + 16 * nt + l15;
      *(float2*)&red[row * 8 + cg * 2] = make_float2(ps[nt], pq[nt]);
    }
  }
  lwait0(); sbar(); schedb();
  float mu[4], rstd[4];
  #pragma unroll
  for (int nt = 0; nt < 4; ++nt) {
    int row = 64 * rg + 16 * nt + l15;
    float s_ = 0.f, q_ = 0.f;
    #pragma unroll
    for (int c = 0; c < 4; ++c) { s_ += red[row * 8 + c * 2]; q_ += red[row * 8 + c * 2 + 1]; }
    float m_ = s_ * (1.f / 256.f);
    float v_ = q_ * (1.f / 256.f) - m_ * m_;
    mu[nt] = m_; rstd[nt] = rsqrtf(v_ + LN_EPS);
  }

  // ---- LN transform in registers: acc := xn ----
  #pragma unroll
  for (int mt = 0; mt < 4; ++mt)
    #pragma unroll
    for (int nt = 0; nt < 4; ++nt) {
      acc[mt][nt][0] = (acc[mt][nt][0] - mu[nt]) * rstd[nt] * g4[mt].x + b4[mt].x;
      acc[mt][nt][1] = (acc[mt][nt][1] - mu[nt]) * rstd[nt] * g4[mt].y + b4[mt].y;
      acc[mt][nt][2] = (acc[mt][nt][2] - mu[nt]) * rstd[nt] * g4[mt].z + b4[mt].z;
      acc[mt][nt][3] = (acc[mt][nt][3] - mu[nt]) * rstd[nt] * g4[mt].w + b4[mt].w;
    }

  float* sred = (float*)U;                 // [4cg][128row] = 2KB
  float* aux  = (float*)(U + 2048);        // [8]
  float* wts  = (float*)(U + 2112);        // [128]
  float* vred = (float*)(U + 3072);        // [2rg][256col] = 2KB
  float* part = ws + WS_PART + (size_t)b * PART_STRIDE;

  // ---- scores: s_i = xn_i . z (all waves) ----
  {
    float4 zf[4];
    #pragma unroll
    for (int mt = 0; mt < 4; ++mt)
      zf[mt] = *(const float4*)&ws[WS_Z + 64 * cg + 16 * mt + 4 * lh];
    float sp[4];
    #pragma unroll
    for (int nt = 0; nt < 4; ++nt) {
      float s_ = 0.f;
      #pragma unroll
      for (int mt = 0; mt < 4; ++mt) {
        s_ = fmaf(zf[mt].x, acc[mt][nt][0], s_);
        s_ = fmaf(zf[mt].y, acc[mt][nt][1], s_);
        s_ = fmaf(zf[mt].z, acc[mt][nt][2], s_);
        s_ = fmaf(zf[mt].w, acc[mt][nt][3], s_);
      }
      sp[nt] = s_;
    }
    #pragma unroll
    for (int nt = 0; nt < 4; ++nt) {
      sp[nt] += __shfl_xor(sp[nt], 16);
      sp[nt] += __shfl_xor(sp[nt], 32);
    }
    if (lh == 0) {
      #pragma unroll
      for (int nt = 0; nt < 4; ++nt) sred[cg * 128 + 64 * rg + 16 * nt + l15] = sp[nt];
    }
  }
  lwait0(); sbar(); schedb();

  // ---- softmax over 128 rows (waves 0,1) ----
  float sv = -INFINITY, ev = 0.f;
  if (tid < 128) {
    sv = sred[tid] + sred[128 + tid] + sred[256 + tid] + sred[384 + tid];
    if (r0 + tid >= N) sv = -INFINITY;
  }
  float mb = sv;
  #pragma unroll
  for (int m = 1; m < 64; m <<= 1) mb = fmaxf(mb, __shfl_xor(mb, m));
  if (tid < 128 && lane == 0) aux[tid >> 6] = mb;
  lwait0(); sbar(); schedb();
  float M2 = fmaxf(aux[0], aux[1]);
  if (tid < 128) { ev = (r0 + tid < N) ? expf(sv - M2) : 0.f; wts[tid] = ev; }
  float lsum = ev;
  #pragma unroll
  for (int m = 1; m < 64; m <<= 1) lsum += __shfl_xor(lsum, m);
  if (tid < 128 && lane == 0) aux[2 + (tid >> 6)] = lsum;
  lwait0(); sbar(); schedb();
  if (tid == 0) { part[PART_M] = M2; part[PART_L] = aux[2] + aux[3]; }

  // ---- y = sum_i w_i * xn_i (all waves; reduce over rows) ----
  {
    float wr[4];
    #pragma unroll
    for (int nt = 0; nt < 4; ++nt) wr[nt] = wts[64 * rg + 16 * nt + l15];
    #pragma unroll
    for (int mt = 0; mt < 4; ++mt) {
      float vs0 = 0.f, vs1 = 0.f, vs2 = 0.f, vs3 = 0.f;
      #pragma unroll
      for (int nt = 0; nt < 4; ++nt) {
        vs0 = fmaf(wr[nt], acc[mt][nt][0], vs0);
        vs1 = fmaf(wr[nt], acc[mt][nt][1], vs1);
        vs2 = fmaf(wr[nt], acc[mt][nt][2], vs2);
        vs3 = fmaf(wr[nt], acc[mt][nt][3], vs3);
      }
      #pragma unroll
      for (int m = 1; m < 16; m <<= 1) {
        vs0 += __shfl_xor(vs0, m); vs1 += __shfl_xor(vs1, m);
        vs2 += __shfl_xor(vs2, m); vs3 += __shfl_xor(vs3, m);
      }
      if (l15 == 0)
        *(float4*)&vred[256 * rg + 64 * cg + 16 * mt + 4 * lh] =
            make_float4(vs0, vs1, vs2, vs3);
    }
  }
  lwait0(); sbar(); schedb();
  if (tid < 256) part[tid] = vred[tid] + vred[256 + tid];
}

// ---------------- K_fin1: per-chunk online-softmax combine of y-partials ----------------
__global__ __launch_bounds__(256) void k_fin1(float* __restrict__ ws, int NB, int chunk)
{
  int g = blockIdx.x, col = threadIdx.x;
  int c0 = g * chunk, c1 = min(c0 + chunk, NB);
  const float* part = ws + WS_PART;
  float mg = -INFINITY;
  for (int bb = c0; bb < c1; ++bb)
    mg = fmaxf(mg, part[(size_t)bb * PART_STRIDE + PART_M]);
  float a = 0.f, lg = 0.f;
  for (int bb = c0; bb < c1; ++bb) {
    float w = expf(part[(size_t)bb * PART_STRIDE + PART_M] - mg);
    a  = fmaf(part[(size_t)bb * PART_STRIDE + col], w, a);
    lg = fmaf(part[(size_t)bb * PART_STRIDE + PART_L], w, lg);
  }
  ws[WS_GP + g * GP_STRIDE + col] = a;
  if (col == 0) {
    ws[WS_GP + g * GP_STRIDE + PART_M] = mg;
    ws[WS_GP + g * GP_STRIDE + PART_L] = lg;
  }
}

// ---------------- K3: global combine + Y@Wv + 2-row FFN head + logits/softmax ----------------
__global__ __launch_bounds__(256) void k_final(
    const float* __restrict__ ws, const float* __restrict__ Wqkv,
    const float* __restrict__ Wf1, const float* __restrict__ bf1,
    const float* __restrict__ Wf2, const float* __restrict__ bf2,
    const float* __restrict__ ln2_g, const float* __restrict__ ln2_b,
    const float* __restrict__ ln3_g, const float* __restrict__ ln3_b,
    const float* __restrict__ Wl1, const float* __restrict__ bl1,
    const float* __restrict__ Wl2, const float* __restrict__ bl2,
    float* __restrict__ out)
{
  __shared__ float rowb[2][128];
  __shared__ float mmb[2][128];
  __shared__ float red[8];
  __shared__ float emb[256];
  __shared__ float abuf[64];
  __shared__ float lbuf[4];
  __shared__ float wg[NCOMB];
  __shared__ float MLs[2];
  __shared__ float Ybuf[256];
  int tid = threadIdx.x, lane = tid & 63, wave = tid >> 6;
  float s0 = ws[WS_S0];

  if (tid == 0) {
    float M = s0;
    for (int g = 0; g < NCOMB; ++g) M = fmaxf(M, ws[WS_GP + g * GP_STRIDE + PART_M]);
    float L = expf(s0 - M);
    for (int g = 0; g < NCOMB; ++g)
      L = fmaf(ws[WS_GP + g * GP_STRIDE + PART_L], expf(ws[WS_GP + g * GP_STRIDE + PART_M] - M), L);
    MLs[0] = M; MLs[1] = L;
  }
  __syncthreads();
  float M = MLs[0], L = MLs[1];
  if (tid < NCOMB) wg[tid] = expf(ws[WS_GP + tid * GP_STRIDE + PART_M] - M);
  __syncthreads();

  {
    float y = 0.f;
    #pragma unroll
    for (int g = 0; g < NCOMB; ++g) y = fmaf(ws[WS_GP + g * GP_STRIDE + tid], wg[g], y);
    Ybuf[tid] = y;
  }
  __syncthreads();

  if (tid < 128) {
    float v0 = ws[WS_V0 + tid];
    float a = v0 * expf(s0 - M);
    for (int c = 0; c < 256; ++c)
      a = fmaf(Ybuf[c], Wqkv[c * 384 + 256 + tid], a);
    rowb[0][tid] = a / L;
    rowb[1][tid] = v0;
  }
  __syncthreads();

  int row = tid >> 7, k = tid & 127;
  float x = rowb[row][k];
  float ps = x, pq = x * x;
  for (int m = 1; m < 64; m <<= 1) { ps += __shfl_xor(ps, m); pq += __shfl_xor(pq, m); }
  __syncthreads();
  if (lane == 0) { red[wave] = ps; red[4 + wave] = pq; }
  __syncthreads();
  {
    float sum = red[row * 2] + red[row * 2 + 1];
    float sq  = red[4 + row * 2] + red[4 + row * 2 + 1];
    float mu = sum * (1.f / 128.f);
    float var = sq * (1.f / 128.f) - mu * mu;
    x = (x - mu) * rsqrtf(var + LN_EPS) * ln2_g[k] + ln2_b[k];
  }
  mmb[row][k] = x;
  __syncthreads();
  float t1 = bf1[k];
  for (int j = 0; j < 128; j++) t1 = fmaf(mmb[row][j], Wf1[j * 128 + k], t1);
  float gg = t1 * 0.5f * (1.f + erff(t1 * 0.70710678118654752f));
  __syncthreads();
  rowb[row][k] = gg;
  __syncthreads();
  float t2 = bf2[k];
  for (int j = 0; j < 128; j++) t2 = fmaf(rowb[row][j], Wf2[j * 128 + k], t2);
  ps = t2; pq = t2 * t2;
  for (int m = 1; m < 64; m <<= 1) { ps += __shfl_xor(ps, m); pq += __shfl_xor(pq, m); }
  __syncthreads();
  if (lane == 0) { red[wave] = ps; red[4 + wave] = pq; }
  __syncthreads();
  {
    float sum = red[row * 2] + red[row * 2 + 1];
    float sq  = red[4 + row * 2] + red[4 + row * 2 + 1];
    float mu = sum * (1.f / 128.f);
    float var = sq * (1.f / 128.f) - mu * mu;
    t2 = (t2 - mu) * rsqrtf(var + LN_EPS) * ln3_g[k] + ln3_b[k];
  }
  emb[row * 128 + k] = t2;
  __syncthreads();
  if (tid < 64) {
    float a = bl1[tid];
    for (int j = 0; j < 256; j++) a = fmaf(emb[j], Wl1[j * 64 + tid], a);
    abuf[tid] = fmaxf(a, 0.f);
  }
  __syncthreads();
  if (tid < 4) {
    float lg = bl2[tid];
    for (int j = 0; j < 64; j++) lg = fmaf(abuf[j], Wl2[j * 4 + tid], lg);
    lbuf[tid] = lg;
  }
  __syncthreads();
  if (tid < 4) {
    float m4 = fmaxf(fmaxf(lbuf[0], lbuf[1]), fmaxf(lbuf[2], lbuf[3]));
    float e0 = expf(lbuf[0] - m4), e1 = expf(lbuf[1] - m4);
    float e2 = expf(lbuf[2] - m4), e3 = expf(lbuf[3] - m4);
    float ssum = e0 + e1 + e2 + e3;
    out[tid] = lbuf[tid];
    out[4 + tid] = expf(lbuf[tid] - m4) / ssum;
  }
}

extern "C" void kernel_launch(void* const* d_in, const int* in_sizes, int n_in,
                              void* d_out, int out_size, void* d_ws, size_t ws_size,
                              hipStream_t stream) {
  const float* wsi    = (const float*)d_in[0];
  const float* x_omic = (const float*)d_in[1];
  const float* W1     = (const float*)d_in[2];
  const float* b1     = (const float*)d_in[3];
  const float* W2     = (const float*)d_in[4];
  const float* b2     = (const float*)d_in[5];
  const float* Wp     = (const float*)d_in[6];
  const float* bp     = (const float*)d_in[7];
  const float* ln1_g  = (const float*)d_in[8];
  const float* ln1_b  = (const float*)d_in[9];
  const float* Wqkv   = (const float*)d_in[10];
  const float* ln2_g  = (const float*)d_in[11];
  const float* ln2_b  = (const float*)d_in[12];
  const float* Wf1    = (const float*)d_in[13];
  const float* bf1    = (const float*)d_in[14];
  const float* Wf2    = (const float*)d_in[15];
  const float* bf2    = (const float*)d_in[16];
  const float* ln3_g  = (const float*)d_in[17];
  const float* ln3_b  = (const float*)d_in[18];
  const float* Wl1    = (const float*)d_in[19];
  const float* bl1    = (const float*)d_in[20];
  const float* Wl2    = (const float*)d_in[21];
  const float* bl2    = (const float*)d_in[22];
  float* ws   = (float*)d_ws;
  float* outp = (float*)d_out;
  ushortT* wpt = (ushortT*)(ws + WS_WPT);

  int N = in_sizes[0] / 1024;
  int d_omic = in_sizes[1];
  int NB = (N + 127) / 128;
  int chunk = (NB + NCOMB - 1) / NCOMB;

  k_setup<<<48, 256, 0, stream>>>(Wp, x_omic, W1, d_omic, wpt, ws);
  k_omic<<<1, 256, 0, stream>>>(b1, W2, b2, Wqkv, ln1_g, ln1_b, ws);
  k_main<<<NB, 512, 0, stream>>>(wsi, N, wpt, bp, ln1_g, ln1_b, ws);
  k_fin1<<<NCOMB, 256, 0, stream>>>(ws, NB, chunk);
  k_final<<<1, 256, 0, stream>>>(ws, Wqkv, Wf1, bf1, Wf2, bf2, ln2_g, ln2_b,
                                 ln3_g, ln3_b, Wl1, bl1, Wl2, bl2, outp);
}